// Round 13
// baseline (3233.727 us; speedup 1.0000x reference)
//
#include <hip/hip_runtime.h>
#include <stdint.h>
#include <stddef.h>

// LSTM: B=64, H=1024, V=4096, T=256
// Phase 0: ONE prep kernel (5 transposes + init, z-sliced grid).
// Phase 1: persistent recurrence kernel, 128 WGs x 256 thr (1 WG/CU, 144KB LDS):
//   - W-slice (32 gate-cols, 64KB) resident in LDS.
//   - mfma(W,H): D rows = gate-cols, cols = batch; r=0..3 = f,i,c,o of one h
//     in one lane (8 exp/lane epilogue, one 16B H-store/row).
//   - A (H rows) via 5-buf LDS ring, PER-WAVE staging, normal cached loads;
//     H stores sc0|sc1 (write-through IF).
//   - Sync: u16 per-WAVE arrival slots (monotone t+1, sc0sc1 store after own
//     vmcnt(0) drain, no RMW, no WG barrier). PIPELINED poll: one dwordx4/lane
//     reads all 512 slots; always one read in flight; exits with EXACTLY one
//     dangling load (registers kept alive past retirement via asm sink).
//   - UNIFORM per-step FIFO at every t: [dangle][S0..S3 x16][tok][xg x8]
//     -> counted vmcnt waits 21/21/21/21/12/8/4/0. xg gathers moved into the
//     step top (issued last) so the poll entry never drains them (round-12's
//     hidden ~0.9us/step stall).
// Phase 2: separate Y-GEMM (16384x4096x1024 bf16) with XCD-swizzled blockIdx.
// Workspace: WcatT 8MB | ywT 8MB | Hbuf (257*64*1024 bf16) 33.7MB | arr 1KB

#define B_ 64
#define H_ 1024
#define V_ 4096
#define T_ 256
#define NWG 128

typedef __attribute__((ext_vector_type(8))) short short8;
typedef __attribute__((ext_vector_type(4))) float f32x4;
typedef __attribute__((ext_vector_type(4))) float float4_;
typedef __attribute__((ext_vector_type(4))) unsigned int uint4v;

static __device__ __forceinline__ unsigned short f2bf(float f) {
  union { float f; unsigned int u; } v; v.f = f;
  unsigned int u = v.u;
  unsigned int r = (u + 0x7fffu + ((u >> 16) & 1u)) >> 16;   // round-to-nearest-even
  return (unsigned short)r;
}

static __device__ __forceinline__ void gload_lds16(const void* g, void* l) {
  // async global->LDS, 16B per lane; LDS dest = wave-uniform base + lane*16
  __builtin_amdgcn_global_load_lds((const __attribute__((address_space(1))) unsigned int*)g,
                                   (__attribute__((address_space(3))) unsigned int*)l,
                                   16, 0, 0);
}

static __device__ __forceinline__ void sc_store_u16(unsigned short* p, unsigned int v) {
  asm volatile("global_store_short %0, %1, off sc0 sc1"
               :: "v"((unsigned long long)p), "v"(v) : "memory");
}

static __device__ __forceinline__ bool ok8(const uint4v& v, unsigned int tgt) {
  return (v[0] & 0xffffu) >= tgt && (v[0] >> 16) >= tgt &&
         (v[1] & 0xffffu) >= tgt && (v[1] >> 16) >= tgt &&
         (v[2] & 0xffffu) >= tgt && (v[2] >> 16) >= tgt &&
         (v[3] & 0xffffu) >= tgt && (v[3] >> 16) >= tgt;
}

// Pipelined wave poll over 512 u16 slots (lane reads 8 slots = one dwordx4 at
// the IF). Always keeps one read in flight; EXITS WITH EXACTLY ONE DANGLING
// LOAD (v0 or v1) — caller must keep v0/v1 registers alive until a counted
// vmcnt wait has retired the dangle (c=0's vmcnt(21) in the K loop).
static __device__ __forceinline__ void pollw16(const unsigned short* arr, unsigned int tgt,
                                               int lane, uint4v& v0, uint4v& v1) {
  const unsigned long long a = (unsigned long long)arr + (unsigned long long)lane * 16u;
  asm volatile("global_load_dwordx4 %0, %1, off sc0 sc1" : "=&v"(v0) : "v"(a) : "memory");
  while (true) {
    asm volatile("global_load_dwordx4 %0, %1, off sc0 sc1\n\ts_waitcnt vmcnt(1)"
                 : "=&v"(v1) : "v"(a) : "memory");
    if (__all(ok8(v0, tgt))) break;     // v1 dangling
    asm volatile("global_load_dwordx4 %0, %1, off sc0 sc1\n\ts_waitcnt vmcnt(1)"
                 : "=&v"(v0) : "v"(a) : "memory");
    if (__all(ok8(v1, tgt))) break;     // v0 dangling
  }
  asm volatile("" ::: "memory");        // no load hoisting above the poll
  __builtin_amdgcn_sched_barrier(0);
}

// ---------------------------------------------------------------------------
// Prep: z=0..3 transpose gate w_hh into Wcat (c=h*4+z); z=4 transpose y_w_ho
// into ywT; z=5 init Hbuf[0] (bf16) + zero 512 u16 arrival slots (sc0sc1).
// grid: (16, 64, 6) x 256 thr; unused (x,y) slices early-exit.
// ---------------------------------------------------------------------------
__global__ void prep_kernel(const float* __restrict__ f_w_hh, const float* __restrict__ i_w_hh,
                            const float* __restrict__ c_w_hh, const float* __restrict__ o_w_hh,
                            const float* __restrict__ y_w_ho,
                            unsigned short* __restrict__ Wcat, unsigned short* __restrict__ ywT,
                            const float* __restrict__ H0, unsigned short* __restrict__ Hbuf0,
                            unsigned short* __restrict__ arr) {
  const int z = blockIdx.z;
  const int t = threadIdx.x;
  if (z == 5) {
    const int b = blockIdx.y * 16 + blockIdx.x;
    if (b < 256) {
      const int i = b * 256 + t;
      Hbuf0[i] = f2bf(H0[i]);
    } else if (b == 256 && t < 512) {
      sc_store_u16(arr + t, 0u);
    }
    return;
  }
  const float* src; unsigned short* dst; int src_cols, c_mul, c_add;
  if (z < 4) {
    if (blockIdx.y >= 16) return;
    src = (z == 0) ? f_w_hh : (z == 1) ? i_w_hh : (z == 2) ? c_w_hh : o_w_hh;
    dst = Wcat; src_cols = 1024; c_mul = 4; c_add = z;
  } else {
    src = y_w_ho; dst = ywT; src_cols = 4096; c_mul = 1; c_add = 0;
  }
  __shared__ float tile[64][65];
  const int k0 = blockIdx.x * 64, h0 = blockIdx.y * 64;
  {
    const int kk = t >> 2, seg = (t & 3) * 16;
    const float* s = src + (size_t)(k0 + kk) * src_cols + h0 + seg;
#pragma unroll
    for (int j = 0; j < 16; j += 4) {
      float4_ v = *(const float4_*)(s + j);
      tile[kk][seg + j + 0] = v[0];
      tile[kk][seg + j + 1] = v[1];
      tile[kk][seg + j + 2] = v[2];
      tile[kk][seg + j + 3] = v[3];
    }
  }
  __syncthreads();
  {
    const int hh = t >> 2, ks = (t & 3) * 16;
    const int c = (h0 + hh) * c_mul + c_add;
    short8 p0, p1;
#pragma unroll
    for (int j = 0; j < 8; ++j) {
      p0[j] = (short)f2bf(tile[ks + j][hh]);
      p1[j] = (short)f2bf(tile[ks + 8 + j][hh]);
    }
    unsigned short* d = dst + (size_t)c * 1024 + k0 + ks;
    *(short8*)(d) = p0;
    *(short8*)(d + 8) = p1;
  }
}

// ---------------------------------------------------------------------------
// Persistent LSTM recurrence. 128 WGs x 256 thr (4 waves).
// LDS: W 64KB @0 | ring 5x16KB @65536 = 144KB.
// ---------------------------------------------------------------------------
#define AOFF 65536

__launch_bounds__(256, 1)
__global__ void lstm_persistent_kernel(
    const unsigned short* __restrict__ Wcat,   // [4096][1024] bf16
    unsigned short* __restrict__ Hbuf,         // [257][64][1024] bf16
    unsigned short* __restrict__ arr,          // [512] u16 per-wave arrival slots
    const float* __restrict__ C0,              // [64][1024] f32
    const float* __restrict__ xwf, const float* __restrict__ xwi,
    const float* __restrict__ xwc, const float* __restrict__ xwo,
    const float* __restrict__ bfv, const float* __restrict__ biv,
    const float* __restrict__ bcv, const float* __restrict__ bov,
    const int* __restrict__ tokens,
    float* __restrict__ outH, float* __restrict__ outC) {
  __shared__ __align__(16) unsigned char lds[147456];
  const int tid = threadIdx.x;
  const int wave = tid >> 6, lane = tid & 63;
  const int l15 = lane & 15, l4 = lane >> 4;
  const int wgc0 = blockIdx.x * 32;
  const int hbase0 = wgc0 >> 2;          // first of this WG's 8 h values
  const int brow = wave * 16 + l15;      // this lane's batch row
  unsigned short* myslot = arr + blockIdx.x * 4 + wave;

  auto xw_of = [&](int g) -> const float* {
    return g == 0 ? xwf : g == 1 ? xwi : g == 2 ? xwc : xwo;
  };
  auto b_of = [&](int g) -> const float* {
    return g == 0 ? bfv : g == 1 ? biv : g == 2 ? bcv : bov;
  };

  // ---- per-lane constants & persistent register state ----
  // mfma(W,H) D layout: col(batch) = l15, row(gate-col) = l4*4 + r.
  // WG cols (c = h*4+g): tile ni covers h = hbase0 + ni*4 + l4, gate = r.
  int hL[2];
  float bias8[2][4], Creg[2], xg[2][4];
#pragma unroll
  for (int ni = 0; ni < 2; ++ni) {
    hL[ni] = hbase0 + ni * 4 + l4;
#pragma unroll
    for (int r = 0; r < 4; ++r) bias8[ni][r] = b_of(r)[hL[ni]];
    Creg[ni] = C0[(size_t)brow * 1024 + hL[ni]];
  }
  int tok2 = tokens[brow * T_ + 0];   // token for step 0 (gathered at t=0 top)

  // ---- stage W-slice into LDS (once), pre-swizzled source ----
  {
    const char* Wb = (const char*)(Wcat + (size_t)wgc0 * 1024);
#pragma unroll
    for (int it = 0; it < 16; ++it) {
      const int D = it * 4096 + wave * 1024 + lane * 16;
      const int row = D >> 11, off = D & 2047;
      const int so = off ^ ((row & 7) << 4);
      gload_lds16(Wb + (size_t)row * 2048 + so, &lds[it * 4096 + wave * 1024]);
    }
  }
  asm volatile("s_waitcnt vmcnt(0)" ::: "memory");
  __syncthreads();   // W visible to all waves (the ONLY workgroup barrier)

  // PER-WAVE staging: wave w stages its own 16 rows of chunk c (A ring),
  // normal cached loads (L2-shared within the XCD).
  auto stageA = [&](int buf, int c, const char* Hsrc) {
#pragma unroll
    for (int it2 = 0; it2 < 4; ++it2) {
      const int row = wave * 16 + it2 * 4 + l4;       // row this lane loads
      const int so = (l15 * 16) ^ ((row & 7) << 4);   // pre-swizzled source
      gload_lds16(Hsrc + (size_t)row * 2048 + c * 256 + so,
                  &lds[AOFF + buf * 16384 + wave * 4096 + it2 * 1024]);
    }
  };

  const int bswz = (l15 & 7) << 4;
  f32x4 acc[2];
  const f32x4 zz = {0.f, 0.f, 0.f, 0.f};
  uint4v pk0 = {0, 0, 0, 0}, pk1 = {0, 0, 0, 0};

#pragma unroll 1
  for (int t = 0; t < T_; ++t) {
    // poll runs at EVERY t (trivially passes at t=0) -> uniform FIFO:
    // [dangle(1)][S0..S3(16)][tok(1)][xg(8)] = 26 outstanding, every step.
    pollw16(arr, (unsigned int)t, lane, pk0, pk1);

    const char* Hs = (const char*)(Hbuf + (size_t)t * 65536);
    // prologue stages: chunks 0..3 -> bufs 0..3 (16 loads/wave)
    stageA(0, 0, Hs);
    stageA(1, 1, Hs);
    stageA(2, 2, Hs);
    stageA(3, 3, Hs);
    __builtin_amdgcn_sched_barrier(0);
    // token for step t+1 (wrapped; value unused at t=T-1)
    const int tok_next = tokens[brow * T_ + ((t + 1) & (T_ - 1))];
    __builtin_amdgcn_sched_barrier(0);
    // xg gathers for THIS step (tok2 = tokens[t], loaded last step) — issued
    // LAST so c=0's wait does not depend on them (they retire at c=4).
#pragma unroll
    for (int ni = 0; ni < 2; ++ni)
#pragma unroll
      for (int r = 0; r < 4; ++r)
        xg[ni][r] = xw_of(r)[(size_t)tok2 * 1024 + hL[ni]];
    __builtin_amdgcn_sched_barrier(0);

    acc[0] = zz; acc[1] = zz;
    // Barrier-free K loop. FIFO trace (uniform at all t):
    // c=0: 26 outst -> vmcnt(21) retires dangle+S0; +S4 -> 25
    // c=1..3: vmcnt(21) retires S_c; +stage -> 25
    // c=4: vmcnt(12) retires tok+xg8+S4; c=5: 8; c=6: 4; c=7: 0.
#pragma unroll
    for (int c = 0; c < 8; ++c) {
      if (c < 4)       asm volatile("s_waitcnt vmcnt(21)" ::: "memory");
      else if (c == 4) asm volatile("s_waitcnt vmcnt(12)" ::: "memory");
      else if (c == 5) asm volatile("s_waitcnt vmcnt(8)" ::: "memory");
      else if (c == 6) asm volatile("s_waitcnt vmcnt(4)" ::: "memory");
      else             asm volatile("s_waitcnt vmcnt(0)" ::: "memory");
      __builtin_amdgcn_sched_barrier(0);
      if (c < 4) stageA((c + 4) % 5, c + 4, Hs);
      __builtin_amdgcn_sched_barrier(0);
      {
        const int abase = AOFF + (c % 5) * 16384;
        const int abyte = abase + brow * 256;           // brow = wave*16+l15
        const int aswz = (brow & 7) << 4;
#pragma unroll
        for (int ks = 0; ks < 4; ++ks) {
          const int koff = ks * 64 + l4 * 16;
          short8 a  = *(const short8*)&lds[abyte + (koff ^ aswz)];            // H frag (B-op)
          short8 b0 = *(const short8*)&lds[(size_t)l15 * 2048 + ((c * 256 + koff) ^ bswz)];        // W frag, tile 0
          short8 b1 = *(const short8*)&lds[(size_t)(16 + l15) * 2048 + ((c * 256 + koff) ^ bswz)]; // W frag, tile 1
          acc[0] = __builtin_amdgcn_mfma_f32_16x16x32_bf16(b0, a, acc[0], 0, 0, 0);
          acc[1] = __builtin_amdgcn_mfma_f32_16x16x32_bf16(b1, a, acc[1], 0, 0, 0);
        }
      }
      __builtin_amdgcn_sched_barrier(0);
    }
    // keep the dangling poll-load registers alive until past their guaranteed
    // retirement (c=0's vmcnt(21)) — prevents in-flight-load reg-reuse clobber.
    asm volatile("" :: "v"(pk0), "v"(pk1));

    tok2 = tok_next;

    // ---- epilogue: per lane, acc[ni][r] = gate r (f,i,c,o) of (brow, hL[ni])
    unsigned short* Hout = Hbuf + (size_t)(t + 1) * 65536;
    unsigned int dat32[2][2];
#pragma unroll
    for (int ni = 0; ni < 2; ++ni) {
      const f32x4 v = acc[ni];
      const float pre0 = v[0] + xg[ni][0] + bias8[ni][0];
      const float pre1 = v[1] + xg[ni][1] + bias8[ni][1];
      const float pre2 = v[2] + xg[ni][2] + bias8[ni][2];
      const float pre3 = v[3] + xg[ni][3] + bias8[ni][3];
      const float pf = 1.f / (1.f + __expf(-pre0));
      const float pi = 1.f / (1.f + __expf(-pre1));
      const float e2 = __expf(2.f * pre2);
      const float pc = (e2 - 1.f) / (e2 + 1.f);
      const float po = 1.f / (1.f + __expf(-pre3));
      const float cn = pf * Creg[ni] + pi * pc;
      Creg[ni] = cn;
      const float hv = po * cn;
      const unsigned int sbf = f2bf(hv);
      // pack 4 h (l4 groups, lane strides of 16) into 2 dwords on l4==0
      const unsigned int p = sbf | (((unsigned int)__shfl_down(sbf, 16)) << 16);
      dat32[ni][0] = p;
      dat32[ni][1] = __shfl_down(p, 32);
      if (t == T_ - 1) {
        const size_t idx = (size_t)brow * 1024 + hL[ni];
        outH[idx] = hv; outC[idx] = cn;
      }
    }
    if (l4 == 0) {   // lanes 0..15: one 16B store covers h hbase0..hbase0+7
      uint4v dat;
      dat.x = dat32[0][0]; dat.y = dat32[0][1];
      dat.z = dat32[1][0]; dat.w = dat32[1][1];
      const unsigned long long addr =
          (unsigned long long)(Hout + (size_t)brow * 1024 + hbase0);
      asm volatile("global_store_dwordx4 %0, %1, off sc0 sc1"
                   :: "v"(addr), "v"(dat) : "memory");
    }

    if (t < T_ - 1) {
      // ---- arrive (per wave): own H stores drained -> slot = t+1 ----
      asm volatile("s_waitcnt vmcnt(0)" ::: "memory");
      if (lane == 0) sc_store_u16(myslot, (unsigned int)(t + 1));
    }
  }
}

// ---------------------------------------------------------------------------
// Y = Hseq(16384x1024 bf16) @ ywT^T + bias -> fp32. m97-style 128x128, BK=32.
// 4096 WGs, XCD-swizzled bid (4096%8==0 -> bijective), waves 2x2, tile 64x64.
// ---------------------------------------------------------------------------
__launch_bounds__(256, 1)
__global__ void out_gemm_kernel(const unsigned short* __restrict__ A,   // [16384][1024] bf16
                                const unsigned short* __restrict__ Bw,  // ywT [4096][1024] bf16
                                const float* __restrict__ bias,         // [4096]
                                float* __restrict__ Yout) {             // [16384][4096] f32
  __shared__ unsigned char Ash[2][8192];   // 128 rows x 64B, XOR-swizzled
  __shared__ unsigned char Bsh[2][8192];
  const int tid = threadIdx.x;
  const int wave = tid >> 6, lane = tid & 63;
  const int wm = wave >> 1, wn = wave & 1;
  const int bid = (blockIdx.x & 7) * 512 + (blockIdx.x >> 3);   // XCD swizzle
  const int tn = bid & 31, tm = bid >> 5;

  const char* Agb = (const char*)(A + (size_t)tm * 128 * 1024);
  const char* Bgb = (const char*)(Bw + (size_t)tn * 128 * 1024);

  f32x4 acc[4][4];
  const f32x4 zz = {0.f, 0.f, 0.f, 0.f};
#pragma unroll
  for (int mi = 0; mi < 4; ++mi)
#pragma unroll
    for (int ni = 0; ni < 4; ++ni) acc[mi][ni] = zz;

  auto stage = [&](int buf, int kc) {
#pragma unroll
    for (int j = 0; j < 2; ++j) {
      const int wbase = wave * 2048 + j * 1024;
      const int D = wbase + lane * 16;
      const int row = D >> 6, off = D & 63;
      const int so = off ^ ((row & 3) << 4);
      gload_lds16(Agb + (size_t)row * 2048 + kc * 64 + so, &Ash[buf][wbase]);
      gload_lds16(Bgb + (size_t)row * 2048 + kc * 64 + so, &Bsh[buf][wbase]);
    }
  };

  stage(0, 0);
  __syncthreads();

#pragma unroll 1
  for (int kc = 0; kc < 32; ++kc) {
    const int cur = kc & 1;
    if (kc < 31) stage(cur ^ 1, kc + 1);
    short8 a[4], b[4];
#pragma unroll
    for (int mi = 0; mi < 4; ++mi) {
      const int row = wm * 64 + mi * 16 + (lane & 15);
      const int off = ((lane >> 4) * 16) ^ ((row & 3) << 4);
      a[mi] = *(const short8*)&Ash[cur][row * 64 + off];
    }
#pragma unroll
    for (int ni = 0; ni < 4; ++ni) {
      const int row = wn * 64 + ni * 16 + (lane & 15);
      const int off = ((lane >> 4) * 16) ^ ((row & 3) << 4);
      b[ni] = *(const short8*)&Bsh[cur][row * 64 + off];
    }
#pragma unroll
    for (int mi = 0; mi < 4; ++mi)
#pragma unroll
      for (int ni = 0; ni < 4; ++ni)
        acc[mi][ni] = __builtin_amdgcn_mfma_f32_16x16x32_bf16(a[mi], b[ni], acc[mi][ni], 0, 0, 0);
    __syncthreads();
  }

  const int l15 = lane & 15, l4 = lane >> 4;
#pragma unroll
  for (int ni = 0; ni < 4; ++ni) {
    const int n = tn * 128 + wn * 64 + ni * 16 + l15;
    const float bv = bias[n];
#pragma unroll
    for (int mi = 0; mi < 4; ++mi) {
#pragma unroll
      for (int r = 0; r < 4; ++r) {
        const int m = tm * 128 + wm * 64 + mi * 16 + l4 * 4 + r;
        Yout[(size_t)m * 4096 + n] = acc[mi][ni][r] + bv;
      }
    }
  }
}

// ---------------------------------------------------------------------------
extern "C" void kernel_launch(void* const* d_in, const int* in_sizes, int n_in,
                              void* d_out, int out_size, void* d_ws, size_t ws_size,
                              hipStream_t stream) {
  const int* tokens   = (const int*)d_in[0];
  const float* H0     = (const float*)d_in[1];
  const float* C0     = (const float*)d_in[2];
  const float* f_w_xh = (const float*)d_in[3];
  const float* f_w_hh = (const float*)d_in[4];
  const float* f_b    = (const float*)d_in[5];
  const float* i_w_xh = (const float*)d_in[6];
  const float* i_w_hh = (const float*)d_in[7];
  const float* i_b    = (const float*)d_in[8];
  const float* c_w_xh = (const float*)d_in[9];
  const float* c_w_hh = (const float*)d_in[10];
  const float* c_b    = (const float*)d_in[11];
  const float* o_w_xh = (const float*)d_in[12];
  const float* o_w_hh = (const float*)d_in[13];
  const float* o_b    = (const float*)d_in[14];
  const float* y_w_ho = (const float*)d_in[15];
  const float* y_b_o  = (const float*)d_in[16];

  char* ws = (char*)d_ws;
  unsigned short* Wcat = (unsigned short*)ws;                         // 8 MB
  unsigned short* ywT  = (unsigned short*)(ws + (size_t)(8u << 20));  // 8 MB
  unsigned short* Hbuf = (unsigned short*)(ws + (size_t)(16u << 20)); // 257*65536*2 B
  unsigned short* arr = (unsigned short*)(ws + (size_t)(16u << 20) + (size_t)257 * 65536 * 2);
  const size_t needed = (size_t)(16u << 20) + (size_t)257 * 65536 * 2 + 1024;
  if (ws_size < needed) return;  // workspace too small: fail visibly

  const dim3 thr(256);
  hipLaunchKernelGGL(prep_kernel, dim3(16, 64, 6), thr, 0, stream,
                     f_w_hh, i_w_hh, c_w_hh, o_w_hh, y_w_ho,
                     Wcat, ywT, H0, Hbuf, arr);

  float* outH = (float*)d_out + (size_t)T_ * B_ * V_;
  hipLaunchKernelGGL(lstm_persistent_kernel, dim3(NWG), thr, 0, stream,
                     Wcat, Hbuf, arr, C0,
                     f_w_xh, i_w_xh, c_w_xh, o_w_xh,
                     f_b, i_b, c_b, o_b,
                     tokens, outH, outH + 65536);

  hipLaunchKernelGGL(out_gemm_kernel, dim3(4096), thr, 0, stream,
                     Hbuf + 65536, ywT, y_b_o, (float*)d_out);
}

// Round 14
// 2944.881 us; speedup vs baseline: 1.0981x; 1.0981x over previous
//
#include <hip/hip_runtime.h>
#include <stdint.h>
#include <stddef.h>

// LSTM: B=64, H=1024, V=4096, T=256
// Phase 0: ONE prep kernel (5 transposes + init, z-sliced grid).
// Phase 1: persistent recurrence kernel, 128 WGs x 256 thr (1 WG/CU, 144KB LDS):
//   - W-slice (32 gate-cols, 64KB) resident in LDS.
//   - mfma(W,H): D rows = gate-cols, cols = batch; r=0..3 = f,i,c,o of one h
//     in one lane (8 exp/lane epilogue, one 16B H-store/row).
//   - A (H rows) via 5-buf LDS ring, PER-WAVE staging, normal cached loads;
//     H stores sc0|sc1 (write-through IF).
//   - Sync: u16 per-WAVE arrival slots (monotone t+1, sc0sc1 store after own
//     vmcnt(0) drain, no RMW, no WG barrier). THROTTLED poll (round-12
//     discipline): ONE dwordx4/lane (all 512 slots) + vmcnt(0) per iteration
//     — the full-RT wait self-throttles poll traffic. Round 13's pipelined
//     vmcnt(1) poll saturated the IF with hot-line reads (1210->3029us).
//   - UNIFORM per-step FIFO at every t: [S0..S3 x16][tok][xg x8] = 25
//     -> counted vmcnt waits 21/21/21/21/12/8/4/0. xg gathers issued at the
//     step top (last) so the poll entry never drains them (round-13 keep).
// Phase 2: separate Y-GEMM (16384x4096x1024 bf16) with XCD-swizzled blockIdx.
// Workspace: WcatT 8MB | ywT 8MB | Hbuf (257*64*1024 bf16) 33.7MB | arr 1KB

#define B_ 64
#define H_ 1024
#define V_ 4096
#define T_ 256
#define NWG 128

typedef __attribute__((ext_vector_type(8))) short short8;
typedef __attribute__((ext_vector_type(4))) float f32x4;
typedef __attribute__((ext_vector_type(4))) float float4_;
typedef __attribute__((ext_vector_type(4))) unsigned int uint4v;

static __device__ __forceinline__ unsigned short f2bf(float f) {
  union { float f; unsigned int u; } v; v.f = f;
  unsigned int u = v.u;
  unsigned int r = (u + 0x7fffu + ((u >> 16) & 1u)) >> 16;   // round-to-nearest-even
  return (unsigned short)r;
}

static __device__ __forceinline__ void gload_lds16(const void* g, void* l) {
  // async global->LDS, 16B per lane; LDS dest = wave-uniform base + lane*16
  __builtin_amdgcn_global_load_lds((const __attribute__((address_space(1))) unsigned int*)g,
                                   (__attribute__((address_space(3))) unsigned int*)l,
                                   16, 0, 0);
}

static __device__ __forceinline__ void sc_store_u16(unsigned short* p, unsigned int v) {
  asm volatile("global_store_short %0, %1, off sc0 sc1"
               :: "v"((unsigned long long)p), "v"(v) : "memory");
}

static __device__ __forceinline__ bool ok8(const uint4v& v, unsigned int tgt) {
  return (v[0] & 0xffffu) >= tgt && (v[0] >> 16) >= tgt &&
         (v[1] & 0xffffu) >= tgt && (v[1] >> 16) >= tgt &&
         (v[2] & 0xffffu) >= tgt && (v[2] >> 16) >= tgt &&
         (v[3] & 0xffffu) >= tgt && (v[3] >> 16) >= tgt;
}

// Throttled wave poll over 512 u16 slots: lane reads 8 slots (one dwordx4 at
// the IF), FULL vmcnt(0) round trip per iteration (self-throttling — do NOT
// pipeline this; round 13 showed vmcnt(1) polling floods the fabric).
// Exits with 0 outstanding VMEM ops.
static __device__ __forceinline__ void pollw16(const unsigned short* arr, unsigned int tgt,
                                               int lane) {
  const unsigned long long a = (unsigned long long)arr + (unsigned long long)lane * 16u;
  while (true) {
    uint4v v;
    asm volatile("global_load_dwordx4 %0, %1, off sc0 sc1\n\ts_waitcnt vmcnt(0)"
                 : "=&v"(v) : "v"(a) : "memory");
    if (__all(ok8(v, tgt))) break;
  }
  asm volatile("" ::: "memory");        // no load hoisting above the poll
  __builtin_amdgcn_sched_barrier(0);
}

// ---------------------------------------------------------------------------
// Prep: z=0..3 transpose gate w_hh into Wcat (c=h*4+z); z=4 transpose y_w_ho
// into ywT; z=5 init Hbuf[0] (bf16) + zero 512 u16 arrival slots (sc0sc1).
// grid: (16, 64, 6) x 256 thr; unused (x,y) slices early-exit.
// ---------------------------------------------------------------------------
__global__ void prep_kernel(const float* __restrict__ f_w_hh, const float* __restrict__ i_w_hh,
                            const float* __restrict__ c_w_hh, const float* __restrict__ o_w_hh,
                            const float* __restrict__ y_w_ho,
                            unsigned short* __restrict__ Wcat, unsigned short* __restrict__ ywT,
                            const float* __restrict__ H0, unsigned short* __restrict__ Hbuf0,
                            unsigned short* __restrict__ arr) {
  const int z = blockIdx.z;
  const int t = threadIdx.x;
  if (z == 5) {
    const int b = blockIdx.y * 16 + blockIdx.x;
    if (b < 256) {
      const int i = b * 256 + t;
      Hbuf0[i] = f2bf(H0[i]);
    } else if (b == 256 && t < 512) {
      sc_store_u16(arr + t, 0u);
    }
    return;
  }
  const float* src; unsigned short* dst; int src_cols, c_mul, c_add;
  if (z < 4) {
    if (blockIdx.y >= 16) return;
    src = (z == 0) ? f_w_hh : (z == 1) ? i_w_hh : (z == 2) ? c_w_hh : o_w_hh;
    dst = Wcat; src_cols = 1024; c_mul = 4; c_add = z;
  } else {
    src = y_w_ho; dst = ywT; src_cols = 4096; c_mul = 1; c_add = 0;
  }
  __shared__ float tile[64][65];
  const int k0 = blockIdx.x * 64, h0 = blockIdx.y * 64;
  {
    const int kk = t >> 2, seg = (t & 3) * 16;
    const float* s = src + (size_t)(k0 + kk) * src_cols + h0 + seg;
#pragma unroll
    for (int j = 0; j < 16; j += 4) {
      float4_ v = *(const float4_*)(s + j);
      tile[kk][seg + j + 0] = v[0];
      tile[kk][seg + j + 1] = v[1];
      tile[kk][seg + j + 2] = v[2];
      tile[kk][seg + j + 3] = v[3];
    }
  }
  __syncthreads();
  {
    const int hh = t >> 2, ks = (t & 3) * 16;
    const int c = (h0 + hh) * c_mul + c_add;
    short8 p0, p1;
#pragma unroll
    for (int j = 0; j < 8; ++j) {
      p0[j] = (short)f2bf(tile[ks + j][hh]);
      p1[j] = (short)f2bf(tile[ks + 8 + j][hh]);
    }
    unsigned short* d = dst + (size_t)c * 1024 + k0 + ks;
    *(short8*)(d) = p0;
    *(short8*)(d + 8) = p1;
  }
}

// ---------------------------------------------------------------------------
// Persistent LSTM recurrence. 128 WGs x 256 thr (4 waves).
// LDS: W 64KB @0 | ring 5x16KB @65536 = 144KB.
// ---------------------------------------------------------------------------
#define AOFF 65536

__launch_bounds__(256, 1)
__global__ void lstm_persistent_kernel(
    const unsigned short* __restrict__ Wcat,   // [4096][1024] bf16
    unsigned short* __restrict__ Hbuf,         // [257][64][1024] bf16
    unsigned short* __restrict__ arr,          // [512] u16 per-wave arrival slots
    const float* __restrict__ C0,              // [64][1024] f32
    const float* __restrict__ xwf, const float* __restrict__ xwi,
    const float* __restrict__ xwc, const float* __restrict__ xwo,
    const float* __restrict__ bfv, const float* __restrict__ biv,
    const float* __restrict__ bcv, const float* __restrict__ bov,
    const int* __restrict__ tokens,
    float* __restrict__ outH, float* __restrict__ outC) {
  __shared__ __align__(16) unsigned char lds[147456];
  const int tid = threadIdx.x;
  const int wave = tid >> 6, lane = tid & 63;
  const int l15 = lane & 15, l4 = lane >> 4;
  const int wgc0 = blockIdx.x * 32;
  const int hbase0 = wgc0 >> 2;          // first of this WG's 8 h values
  const int brow = wave * 16 + l15;      // this lane's batch row
  unsigned short* myslot = arr + blockIdx.x * 4 + wave;

  auto xw_of = [&](int g) -> const float* {
    return g == 0 ? xwf : g == 1 ? xwi : g == 2 ? xwc : xwo;
  };
  auto b_of = [&](int g) -> const float* {
    return g == 0 ? bfv : g == 1 ? biv : g == 2 ? bcv : bov;
  };

  // ---- per-lane constants & persistent register state ----
  // mfma(W,H) D layout: col(batch) = l15, row(gate-col) = l4*4 + r.
  // WG cols (c = h*4+g): tile ni covers h = hbase0 + ni*4 + l4, gate = r.
  int hL[2];
  float bias8[2][4], Creg[2], xg[2][4];
#pragma unroll
  for (int ni = 0; ni < 2; ++ni) {
    hL[ni] = hbase0 + ni * 4 + l4;
#pragma unroll
    for (int r = 0; r < 4; ++r) bias8[ni][r] = b_of(r)[hL[ni]];
    Creg[ni] = C0[(size_t)brow * 1024 + hL[ni]];
  }
  int tok2 = tokens[brow * T_ + 0];   // token for step 0 (gathered at t=0 top)

  // ---- stage W-slice into LDS (once), pre-swizzled source ----
  {
    const char* Wb = (const char*)(Wcat + (size_t)wgc0 * 1024);
#pragma unroll
    for (int it = 0; it < 16; ++it) {
      const int D = it * 4096 + wave * 1024 + lane * 16;
      const int row = D >> 11, off = D & 2047;
      const int so = off ^ ((row & 7) << 4);
      gload_lds16(Wb + (size_t)row * 2048 + so, &lds[it * 4096 + wave * 1024]);
    }
  }
  asm volatile("s_waitcnt vmcnt(0)" ::: "memory");
  __syncthreads();   // W visible to all waves (the ONLY workgroup barrier)

  // PER-WAVE staging: wave w stages its own 16 rows of chunk c (A ring),
  // normal cached loads (L2-shared within the XCD).
  auto stageA = [&](int buf, int c, const char* Hsrc) {
#pragma unroll
    for (int it2 = 0; it2 < 4; ++it2) {
      const int row = wave * 16 + it2 * 4 + l4;       // row this lane loads
      const int so = (l15 * 16) ^ ((row & 7) << 4);   // pre-swizzled source
      gload_lds16(Hsrc + (size_t)row * 2048 + c * 256 + so,
                  &lds[AOFF + buf * 16384 + wave * 4096 + it2 * 1024]);
    }
  };

  const int bswz = (l15 & 7) << 4;
  f32x4 acc[2];
  const f32x4 zz = {0.f, 0.f, 0.f, 0.f};

#pragma unroll 1
  for (int t = 0; t < T_; ++t) {
    // poll runs at EVERY t (trivially passes at t=0); exits with 0 VMEM
    // outstanding -> uniform per-step FIFO below.
    pollw16(arr, (unsigned int)t, lane);

    const char* Hs = (const char*)(Hbuf + (size_t)t * 65536);
    // prologue stages: chunks 0..3 -> bufs 0..3 (16 loads/wave)
    stageA(0, 0, Hs);
    stageA(1, 1, Hs);
    stageA(2, 2, Hs);
    stageA(3, 3, Hs);
    __builtin_amdgcn_sched_barrier(0);
    // token for step t+1 (wrapped; value unused at t=T-1)
    const int tok_next = tokens[brow * T_ + ((t + 1) & (T_ - 1))];
    __builtin_amdgcn_sched_barrier(0);
    // xg gathers for THIS step (tok2 = tokens[t], loaded last step) — issued
    // LAST so c=0's wait does not depend on them (they retire at c=4).
#pragma unroll
    for (int ni = 0; ni < 2; ++ni)
#pragma unroll
      for (int r = 0; r < 4; ++r)
        xg[ni][r] = xw_of(r)[(size_t)tok2 * 1024 + hL[ni]];
    __builtin_amdgcn_sched_barrier(0);

    acc[0] = zz; acc[1] = zz;
    // Barrier-free K loop. FIFO trace (uniform at all t; 25 outstanding at
    // c=0): [S0..S3(16)][tok(1)][xg(8)]; +4 per in-loop stage.
    // c=0..3: vmcnt(21) retires exactly S_c; c=4: vmcnt(12) retires
    // tok+xg8+S4; c=5: 8; c=6: 4; c=7: 0.
#pragma unroll
    for (int c = 0; c < 8; ++c) {
      if (c < 4)       asm volatile("s_waitcnt vmcnt(21)" ::: "memory");
      else if (c == 4) asm volatile("s_waitcnt vmcnt(12)" ::: "memory");
      else if (c == 5) asm volatile("s_waitcnt vmcnt(8)" ::: "memory");
      else if (c == 6) asm volatile("s_waitcnt vmcnt(4)" ::: "memory");
      else             asm volatile("s_waitcnt vmcnt(0)" ::: "memory");
      __builtin_amdgcn_sched_barrier(0);
      if (c < 4) stageA((c + 4) % 5, c + 4, Hs);
      __builtin_amdgcn_sched_barrier(0);
      {
        const int abase = AOFF + (c % 5) * 16384;
        const int abyte = abase + brow * 256;           // brow = wave*16+l15
        const int aswz = (brow & 7) << 4;
#pragma unroll
        for (int ks = 0; ks < 4; ++ks) {
          const int koff = ks * 64 + l4 * 16;
          short8 a  = *(const short8*)&lds[abyte + (koff ^ aswz)];            // H frag (B-op)
          short8 b0 = *(const short8*)&lds[(size_t)l15 * 2048 + ((c * 256 + koff) ^ bswz)];        // W frag, tile 0
          short8 b1 = *(const short8*)&lds[(size_t)(16 + l15) * 2048 + ((c * 256 + koff) ^ bswz)]; // W frag, tile 1
          acc[0] = __builtin_amdgcn_mfma_f32_16x16x32_bf16(b0, a, acc[0], 0, 0, 0);
          acc[1] = __builtin_amdgcn_mfma_f32_16x16x32_bf16(b1, a, acc[1], 0, 0, 0);
        }
      }
      __builtin_amdgcn_sched_barrier(0);
    }

    tok2 = tok_next;

    // ---- epilogue: per lane, acc[ni][r] = gate r (f,i,c,o) of (brow, hL[ni])
    unsigned short* Hout = Hbuf + (size_t)(t + 1) * 65536;
    unsigned int dat32[2][2];
#pragma unroll
    for (int ni = 0; ni < 2; ++ni) {
      const f32x4 v = acc[ni];
      const float pre0 = v[0] + xg[ni][0] + bias8[ni][0];
      const float pre1 = v[1] + xg[ni][1] + bias8[ni][1];
      const float pre2 = v[2] + xg[ni][2] + bias8[ni][2];
      const float pre3 = v[3] + xg[ni][3] + bias8[ni][3];
      const float pf = 1.f / (1.f + __expf(-pre0));
      const float pi = 1.f / (1.f + __expf(-pre1));
      const float e2 = __expf(2.f * pre2);
      const float pc = (e2 - 1.f) / (e2 + 1.f);
      const float po = 1.f / (1.f + __expf(-pre3));
      const float cn = pf * Creg[ni] + pi * pc;
      Creg[ni] = cn;
      const float hv = po * cn;
      const unsigned int sbf = f2bf(hv);
      // pack 4 h (l4 groups, lane strides of 16) into 2 dwords on l4==0
      const unsigned int p = sbf | (((unsigned int)__shfl_down(sbf, 16)) << 16);
      dat32[ni][0] = p;
      dat32[ni][1] = __shfl_down(p, 32);
      if (t == T_ - 1) {
        const size_t idx = (size_t)brow * 1024 + hL[ni];
        outH[idx] = hv; outC[idx] = cn;
      }
    }
    if (l4 == 0) {   // lanes 0..15: one 16B store covers h hbase0..hbase0+7
      uint4v dat;
      dat.x = dat32[0][0]; dat.y = dat32[0][1];
      dat.z = dat32[1][0]; dat.w = dat32[1][1];
      const unsigned long long addr =
          (unsigned long long)(Hout + (size_t)brow * 1024 + hbase0);
      asm volatile("global_store_dwordx4 %0, %1, off sc0 sc1"
                   :: "v"(addr), "v"(dat) : "memory");
    }

    if (t < T_ - 1) {
      // ---- arrive (per wave): own H stores drained -> slot = t+1 ----
      asm volatile("s_waitcnt vmcnt(0)" ::: "memory");
      if (lane == 0) sc_store_u16(myslot, (unsigned int)(t + 1));
    }
  }
}

// ---------------------------------------------------------------------------
// Y = Hseq(16384x1024 bf16) @ ywT^T + bias -> fp32. m97-style 128x128, BK=32.
// 4096 WGs, XCD-swizzled bid (4096%8==0 -> bijective), waves 2x2, tile 64x64.
// ---------------------------------------------------------------------------
__launch_bounds__(256, 1)
__global__ void out_gemm_kernel(const unsigned short* __restrict__ A,   // [16384][1024] bf16
                                const unsigned short* __restrict__ Bw,  // ywT [4096][1024] bf16
                                const float* __restrict__ bias,         // [4096]
                                float* __restrict__ Yout) {             // [16384][4096] f32
  __shared__ unsigned char Ash[2][8192];   // 128 rows x 64B, XOR-swizzled
  __shared__ unsigned char Bsh[2][8192];
  const int tid = threadIdx.x;
  const int wave = tid >> 6, lane = tid & 63;
  const int wm = wave >> 1, wn = wave & 1;
  const int bid = (blockIdx.x & 7) * 512 + (blockIdx.x >> 3);   // XCD swizzle
  const int tn = bid & 31, tm = bid >> 5;

  const char* Agb = (const char*)(A + (size_t)tm * 128 * 1024);
  const char* Bgb = (const char*)(Bw + (size_t)tn * 128 * 1024);

  f32x4 acc[4][4];
  const f32x4 zz = {0.f, 0.f, 0.f, 0.f};
#pragma unroll
  for (int mi = 0; mi < 4; ++mi)
#pragma unroll
    for (int ni = 0; ni < 4; ++ni) acc[mi][ni] = zz;

  auto stage = [&](int buf, int kc) {
#pragma unroll
    for (int j = 0; j < 2; ++j) {
      const int wbase = wave * 2048 + j * 1024;
      const int D = wbase + lane * 16;
      const int row = D >> 6, off = D & 63;
      const int so = off ^ ((row & 3) << 4);
      gload_lds16(Agb + (size_t)row * 2048 + kc * 64 + so, &Ash[buf][wbase]);
      gload_lds16(Bgb + (size_t)row * 2048 + kc * 64 + so, &Bsh[buf][wbase]);
    }
  };

  stage(0, 0);
  __syncthreads();

#pragma unroll 1
  for (int kc = 0; kc < 32; ++kc) {
    const int cur = kc & 1;
    if (kc < 31) stage(cur ^ 1, kc + 1);
    short8 a[4], b[4];
#pragma unroll
    for (int mi = 0; mi < 4; ++mi) {
      const int row = wm * 64 + mi * 16 + (lane & 15);
      const int off = ((lane >> 4) * 16) ^ ((row & 3) << 4);
      a[mi] = *(const short8*)&Ash[cur][row * 64 + off];
    }
#pragma unroll
    for (int ni = 0; ni < 4; ++ni) {
      const int row = wn * 64 + ni * 16 + (lane & 15);
      const int off = ((lane >> 4) * 16) ^ ((row & 3) << 4);
      b[ni] = *(const short8*)&Bsh[cur][row * 64 + off];
    }
#pragma unroll
    for (int mi = 0; mi < 4; ++mi)
#pragma unroll
      for (int ni = 0; ni < 4; ++ni)
        acc[mi][ni] = __builtin_amdgcn_mfma_f32_16x16x32_bf16(a[mi], b[ni], acc[mi][ni], 0, 0, 0);
    __syncthreads();
  }

  const int l15 = lane & 15, l4 = lane >> 4;
#pragma unroll
  for (int ni = 0; ni < 4; ++ni) {
    const int n = tn * 128 + wn * 64 + ni * 16 + l15;
    const float bv = bias[n];
#pragma unroll
    for (int mi = 0; mi < 4; ++mi) {
#pragma unroll
      for (int r = 0; r < 4; ++r) {
        const int m = tm * 128 + wm * 64 + mi * 16 + l4 * 4 + r;
        Yout[(size_t)m * 4096 + n] = acc[mi][ni][r] + bv;
      }
    }
  }
}

// ---------------------------------------------------------------------------
extern "C" void kernel_launch(void* const* d_in, const int* in_sizes, int n_in,
                              void* d_out, int out_size, void* d_ws, size_t ws_size,
                              hipStream_t stream) {
  const int* tokens   = (const int*)d_in[0];
  const float* H0     = (const float*)d_in[1];
  const float* C0     = (const float*)d_in[2];
  const float* f_w_xh = (const float*)d_in[3];
  const float* f_w_hh = (const float*)d_in[4];
  const float* f_b    = (const float*)d_in[5];
  const float* i_w_xh = (const float*)d_in[6];
  const float* i_w_hh = (const float*)d_in[7];
  const float* i_b    = (const float*)d_in[8];
  const float* c_w_xh = (const float*)d_in[9];
  const float* c_w_hh = (const float*)d_in[10];
  const float* c_b    = (const float*)d_in[11];
  const float* o_w_xh = (const float*)d_in[12];
  const float* o_w_hh = (const float*)d_in[13];
  const float* o_b    = (const float*)d_in[14];
  const float* y_w_ho = (const float*)d_in[15];
  const float* y_b_o  = (const float*)d_in[16];

  char* ws = (char*)d_ws;
  unsigned short* Wcat = (unsigned short*)ws;                         // 8 MB
  unsigned short* ywT  = (unsigned short*)(ws + (size_t)(8u << 20));  // 8 MB
  unsigned short* Hbuf = (unsigned short*)(ws + (size_t)(16u << 20)); // 257*65536*2 B
  unsigned short* arr = (unsigned short*)(ws + (size_t)(16u << 20) + (size_t)257 * 65536 * 2);
  const size_t needed = (size_t)(16u << 20) + (size_t)257 * 65536 * 2 + 1024;
  if (ws_size < needed) return;  // workspace too small: fail visibly

  const dim3 thr(256);
  hipLaunchKernelGGL(prep_kernel, dim3(16, 64, 6), thr, 0, stream,
                     f_w_hh, i_w_hh, c_w_hh, o_w_hh, y_w_ho,
                     Wcat, ywT, H0, Hbuf, arr);

  float* outH = (float*)d_out + (size_t)T_ * B_ * V_;
  hipLaunchKernelGGL(lstm_persistent_kernel, dim3(NWG), thr, 0, stream,
                     Wcat, Hbuf, arr, C0,
                     f_w_xh, i_w_xh, c_w_xh, o_w_xh,
                     f_b, i_b, c_b, o_b,
                     tokens, outH, outH + 65536);

  hipLaunchKernelGGL(out_gemm_kernel, dim3(4096), thr, 0, stream,
                     Hbuf + 65536, ywT, y_b_o, (float*)d_out);
}

// Round 15
// 1366.315 us; speedup vs baseline: 2.3668x; 2.1553x over previous
//
#include <hip/hip_runtime.h>
#include <stdint.h>
#include <stddef.h>

// LSTM: B=64, H=1024, V=4096, T=256
// Phase 0: ONE prep kernel (5 transposes + init, z-sliced grid).
// Phase 1: persistent recurrence kernel, 128 WGs x 256 thr (1 WG/CU, 144KB LDS)
//   == EXACT round-12 loop (best measured: 1210us recurrence) ==
//   - W-slice (32 gate-cols, 64KB) resident in LDS.
//   - mfma(W,H): D rows = gate-cols, cols = batch; r=0..3 = f,i,c,o of one h
//     in one lane (8 exp/lane epilogue, one 16B H-store/row).
//   - A (H rows) via 5-buf LDS ring, PER-WAVE staging, normal cached loads;
//     H stores sc0|sc1 (write-through IF).
//   - Sync: u32 per-WAVE arrival slots (monotone t+1, sc0sc1 store after own
//     vmcnt(0) drain, no RMW, no WG barrier). THROTTLED poll at t>0: two
//     dwordx4/lane (512 u32 slots) + vmcnt(0) per iteration. The poll's
//     vmcnt(0) deliberately overlaps draining the PREVIOUS step's xgn
//     gathers + arrival-store ack with the poll read (one shared fabric RT).
//   - xgn (next-step x-gathers) issued at step END, after the arrival store
//     (r13/r14 lesson: moving them to the step top serializes chunk 4-7
//     retirement behind gather latency + synchronizes the gather burst —
//     1210 -> 2900us. FIFO position matters as much as issue count.)
//   - Barrier-free K loop; per-wave vmcnt FIFO [S0..S3 x16][tok] = 17
//     -> counted waits 13/13/13/13/12/8/4/0, uniform at every t.
// Phase 2: separate Y-GEMM (16384x4096x1024 bf16), XCD-swizzled blockIdx.
// Workspace: WcatT 8MB | ywT 8MB | Hbuf (257*64*1024 bf16) 33.7MB | arr 2KB

#define B_ 64
#define H_ 1024
#define V_ 4096
#define T_ 256
#define NWG 128

typedef __attribute__((ext_vector_type(8))) short short8;
typedef __attribute__((ext_vector_type(4))) float f32x4;
typedef __attribute__((ext_vector_type(4))) float float4_;
typedef __attribute__((ext_vector_type(4))) unsigned int uint4v;

static __device__ __forceinline__ unsigned short f2bf(float f) {
  union { float f; unsigned int u; } v; v.f = f;
  unsigned int u = v.u;
  unsigned int r = (u + 0x7fffu + ((u >> 16) & 1u)) >> 16;   // round-to-nearest-even
  return (unsigned short)r;
}

static __device__ __forceinline__ void gload_lds16(const void* g, void* l) {
  // async global->LDS, 16B per lane; LDS dest = wave-uniform base + lane*16
  __builtin_amdgcn_global_load_lds((const __attribute__((address_space(1))) unsigned int*)g,
                                   (__attribute__((address_space(3))) unsigned int*)l,
                                   16, 0, 0);
}

static __device__ __forceinline__ void sc_store_u32(unsigned int* p, unsigned int v) {
  asm volatile("global_store_dword %0, %1, off sc0 sc1"
               :: "v"((unsigned long long)p), "v"(v) : "memory");
}

static __device__ __forceinline__ bool ok4(const uint4v& v, unsigned int tgt) {
  return v[0] >= tgt && v[1] >= tgt && v[2] >= tgt && v[3] >= tgt;
}

// Throttled wave poll over 512 u32 slots: lane reads slots [4l..4l+3] and
// [256+4l..256+4l+3] (two dwordx4 at the IF), FULL vmcnt(0) per iteration
// (self-throttling — round 13 showed pipelined vmcnt(1) polling floods the
// fabric). Exits with 0 outstanding VMEM ops.
static __device__ __forceinline__ void pollw(const unsigned int* arr, unsigned int tgt,
                                             int lane) {
  const unsigned long long a0 = (unsigned long long)arr + (unsigned long long)lane * 16u;
  const unsigned long long a1 = a0 + 1024u;
  while (true) {
    uint4v v0, v1;
    asm volatile("global_load_dwordx4 %0, %2, off sc0 sc1\n\t"
                 "global_load_dwordx4 %1, %3, off sc0 sc1\n\t"
                 "s_waitcnt vmcnt(0)"
                 : "=&v"(v0), "=&v"(v1) : "v"(a0), "v"(a1) : "memory");
    if (__all(ok4(v0, tgt) && ok4(v1, tgt))) break;
  }
  asm volatile("" ::: "memory");        // no load hoisting above the poll
  __builtin_amdgcn_sched_barrier(0);
}

// ---------------------------------------------------------------------------
// Prep: z=0..3 transpose gate w_hh into Wcat (c=h*4+z); z=4 transpose y_w_ho
// into ywT; z=5 init Hbuf[0] (bf16) + zero 512 u32 arrival slots (sc0sc1).
// grid: (16, 64, 6) x 256 thr; unused (x,y) slices early-exit.
// ---------------------------------------------------------------------------
__global__ void prep_kernel(const float* __restrict__ f_w_hh, const float* __restrict__ i_w_hh,
                            const float* __restrict__ c_w_hh, const float* __restrict__ o_w_hh,
                            const float* __restrict__ y_w_ho,
                            unsigned short* __restrict__ Wcat, unsigned short* __restrict__ ywT,
                            const float* __restrict__ H0, unsigned short* __restrict__ Hbuf0,
                            unsigned int* __restrict__ arr) {
  const int z = blockIdx.z;
  const int t = threadIdx.x;
  if (z == 5) {
    const int b = blockIdx.y * 16 + blockIdx.x;
    if (b < 256) {
      const int i = b * 256 + t;
      Hbuf0[i] = f2bf(H0[i]);
    } else if (b == 256 && t < 512) {
      sc_store_u32(arr + t, 0u);
    }
    return;
  }
  const float* src; unsigned short* dst; int src_cols, c_mul, c_add;
  if (z < 4) {
    if (blockIdx.y >= 16) return;
    src = (z == 0) ? f_w_hh : (z == 1) ? i_w_hh : (z == 2) ? c_w_hh : o_w_hh;
    dst = Wcat; src_cols = 1024; c_mul = 4; c_add = z;
  } else {
    src = y_w_ho; dst = ywT; src_cols = 4096; c_mul = 1; c_add = 0;
  }
  __shared__ float tile[64][65];
  const int k0 = blockIdx.x * 64, h0 = blockIdx.y * 64;
  {
    const int kk = t >> 2, seg = (t & 3) * 16;
    const float* s = src + (size_t)(k0 + kk) * src_cols + h0 + seg;
#pragma unroll
    for (int j = 0; j < 16; j += 4) {
      float4_ v = *(const float4_*)(s + j);
      tile[kk][seg + j + 0] = v[0];
      tile[kk][seg + j + 1] = v[1];
      tile[kk][seg + j + 2] = v[2];
      tile[kk][seg + j + 3] = v[3];
    }
  }
  __syncthreads();
  {
    const int hh = t >> 2, ks = (t & 3) * 16;
    const int c = (h0 + hh) * c_mul + c_add;
    short8 p0, p1;
#pragma unroll
    for (int j = 0; j < 8; ++j) {
      p0[j] = (short)f2bf(tile[ks + j][hh]);
      p1[j] = (short)f2bf(tile[ks + 8 + j][hh]);
    }
    unsigned short* d = dst + (size_t)c * 1024 + k0 + ks;
    *(short8*)(d) = p0;
    *(short8*)(d + 8) = p1;
  }
}

// ---------------------------------------------------------------------------
// Persistent LSTM recurrence. 128 WGs x 256 thr (4 waves).
// LDS: W 64KB @0 | ring 5x16KB @65536 = 144KB.
// ---------------------------------------------------------------------------
#define AOFF 65536

__launch_bounds__(256, 1)
__global__ void lstm_persistent_kernel(
    const unsigned short* __restrict__ Wcat,   // [4096][1024] bf16
    unsigned short* __restrict__ Hbuf,         // [257][64][1024] bf16
    unsigned int* __restrict__ arr,            // [512] u32 per-wave arrival slots
    const float* __restrict__ C0,              // [64][1024] f32
    const float* __restrict__ xwf, const float* __restrict__ xwi,
    const float* __restrict__ xwc, const float* __restrict__ xwo,
    const float* __restrict__ bfv, const float* __restrict__ biv,
    const float* __restrict__ bcv, const float* __restrict__ bov,
    const int* __restrict__ tokens,
    float* __restrict__ outH, float* __restrict__ outC) {
  __shared__ __align__(16) unsigned char lds[147456];
  const int tid = threadIdx.x;
  const int wave = tid >> 6, lane = tid & 63;
  const int l15 = lane & 15, l4 = lane >> 4;
  const int wgc0 = blockIdx.x * 32;
  const int hbase0 = wgc0 >> 2;          // first of this WG's 8 h values
  const int brow = wave * 16 + l15;      // this lane's batch row
  unsigned int* myslot = arr + blockIdx.x * 4 + wave;

  auto xw_of = [&](int g) -> const float* {
    return g == 0 ? xwf : g == 1 ? xwi : g == 2 ? xwc : xwo;
  };
  auto b_of = [&](int g) -> const float* {
    return g == 0 ? bfv : g == 1 ? biv : g == 2 ? bcv : bov;
  };

  // ---- per-lane constants & persistent register state ----
  // mfma(W,H) D layout: col(batch) = l15, row(gate-col) = l4*4 + r.
  // WG cols (c = h*4+g): tile ni covers h = hbase0 + ni*4 + l4, gate = r.
  int hL[2];
  float bias8[2][4], Creg[2], xg[2][4], xgn[2][4];
#pragma unroll
  for (int ni = 0; ni < 2; ++ni) {
    hL[ni] = hbase0 + ni * 4 + l4;
#pragma unroll
    for (int r = 0; r < 4; ++r) bias8[ni][r] = b_of(r)[hL[ni]];
    Creg[ni] = C0[(size_t)brow * 1024 + hL[ni]];
  }
  {
    const int tk = tokens[brow * T_ + 0];
#pragma unroll
    for (int ni = 0; ni < 2; ++ni)
#pragma unroll
      for (int r = 0; r < 4; ++r)
        xg[ni][r] = xw_of(r)[(size_t)tk * 1024 + hL[ni]];
  }

  // ---- stage W-slice into LDS (once), pre-swizzled source ----
  {
    const char* Wb = (const char*)(Wcat + (size_t)wgc0 * 1024);
#pragma unroll
    for (int it = 0; it < 16; ++it) {
      const int D = it * 4096 + wave * 1024 + lane * 16;
      const int row = D >> 11, off = D & 2047;
      const int so = off ^ ((row & 7) << 4);
      gload_lds16(Wb + (size_t)row * 2048 + so, &lds[it * 4096 + wave * 1024]);
    }
  }
  asm volatile("s_waitcnt vmcnt(0)" ::: "memory");
  __syncthreads();   // W visible to all waves (the ONLY workgroup barrier)

  // PER-WAVE staging: wave w stages its own 16 rows of chunk c (A ring),
  // normal cached loads (L2-shared within the XCD).
  auto stageA = [&](int buf, int c, const char* Hsrc) {
#pragma unroll
    for (int it2 = 0; it2 < 4; ++it2) {
      const int row = wave * 16 + it2 * 4 + l4;       // row this lane loads
      const int so = (l15 * 16) ^ ((row & 7) << 4);   // pre-swizzled source
      gload_lds16(Hsrc + (size_t)row * 2048 + c * 256 + so,
                  &lds[AOFF + buf * 16384 + wave * 4096 + it2 * 1024]);
    }
  };

  const int bswz = (l15 & 7) << 4;
  f32x4 acc[2];
  const f32x4 zz = {0.f, 0.f, 0.f, 0.f};

#pragma unroll 1
  for (int t = 0; t < T_; ++t) {
    // poll (t>0): exits with 0 VMEM outstanding. Its internal vmcnt(0)
    // overlaps draining last step's xgn gathers + arrival-store ack with
    // the poll read — one shared fabric round trip (do NOT move xgn).
    if (t > 0) pollw(arr, (unsigned int)t, lane);

    const char* Hs = (const char*)(Hbuf + (size_t)t * 65536);
    // prologue stages: chunks 0..3 -> bufs 0..3 (16 loads/wave)
    stageA(0, 0, Hs);
    stageA(1, 1, Hs);
    stageA(2, 2, Hs);
    stageA(3, 3, Hs);

    // UNCONDITIONAL token load (wrapped; value unused at t=T-1) pinned AFTER
    // the stages so the per-step vmcnt FIFO is identical at every t.
    __builtin_amdgcn_sched_barrier(0);
    const int tok2 = tokens[brow * T_ + ((t + 1) & (T_ - 1))];
    __builtin_amdgcn_sched_barrier(0);

    acc[0] = zz; acc[1] = zz;
    // Barrier-free K loop. FIFO (uniform at all t): [S0..S3(16)][tok(1)] = 17
    // at c=0; +4 per in-loop stage. c=0..3: vmcnt(13) retires exactly S_c;
    // c=4: vmcnt(12) retires tok+S4; c=5: 8 -> S5; c=6: 4 -> S6; c=7: 0 -> S7.
#pragma unroll
    for (int c = 0; c < 8; ++c) {
      if (c < 4)       asm volatile("s_waitcnt vmcnt(13)" ::: "memory");
      else if (c == 4) asm volatile("s_waitcnt vmcnt(12)" ::: "memory");
      else if (c == 5) asm volatile("s_waitcnt vmcnt(8)" ::: "memory");
      else if (c == 6) asm volatile("s_waitcnt vmcnt(4)" ::: "memory");
      else             asm volatile("s_waitcnt vmcnt(0)" ::: "memory");
      __builtin_amdgcn_sched_barrier(0);
      if (c < 4) stageA((c + 4) % 5, c + 4, Hs);
      __builtin_amdgcn_sched_barrier(0);
      {
        const int abase = AOFF + (c % 5) * 16384;
        const int abyte = abase + brow * 256;           // brow = wave*16+l15
        const int aswz = (brow & 7) << 4;
#pragma unroll
        for (int ks = 0; ks < 4; ++ks) {
          const int koff = ks * 64 + l4 * 16;
          short8 a  = *(const short8*)&lds[abyte + (koff ^ aswz)];            // H frag (B-op)
          short8 b0 = *(const short8*)&lds[(size_t)l15 * 2048 + ((c * 256 + koff) ^ bswz)];        // W frag, tile 0
          short8 b1 = *(const short8*)&lds[(size_t)(16 + l15) * 2048 + ((c * 256 + koff) ^ bswz)]; // W frag, tile 1
          acc[0] = __builtin_amdgcn_mfma_f32_16x16x32_bf16(b0, a, acc[0], 0, 0, 0);
          acc[1] = __builtin_amdgcn_mfma_f32_16x16x32_bf16(b1, a, acc[1], 0, 0, 0);
        }
      }
      __builtin_amdgcn_sched_barrier(0);
    }

    // xg for this step: t=0 preloaded; t>0 from prefetch issued last iteration
    if (t > 0) {
#pragma unroll
      for (int ni = 0; ni < 2; ++ni)
#pragma unroll
        for (int r = 0; r < 4; ++r) xg[ni][r] = xgn[ni][r];
    }

    // ---- epilogue: per lane, acc[ni][r] = gate r (f,i,c,o) of (brow, hL[ni])
    unsigned short* Hout = Hbuf + (size_t)(t + 1) * 65536;
    unsigned int dat32[2][2];
#pragma unroll
    for (int ni = 0; ni < 2; ++ni) {
      const f32x4 v = acc[ni];
      const float pre0 = v[0] + xg[ni][0] + bias8[ni][0];
      const float pre1 = v[1] + xg[ni][1] + bias8[ni][1];
      const float pre2 = v[2] + xg[ni][2] + bias8[ni][2];
      const float pre3 = v[3] + xg[ni][3] + bias8[ni][3];
      const float pf = 1.f / (1.f + __expf(-pre0));
      const float pi = 1.f / (1.f + __expf(-pre1));
      const float e2 = __expf(2.f * pre2);
      const float pc = (e2 - 1.f) / (e2 + 1.f);
      const float po = 1.f / (1.f + __expf(-pre3));
      const float cn = pf * Creg[ni] + pi * pc;
      Creg[ni] = cn;
      const float hv = po * cn;
      const unsigned int sbf = f2bf(hv);
      // pack 4 h (l4 groups, lane strides of 16) into 2 dwords on l4==0
      const unsigned int p = sbf | (((unsigned int)__shfl_down(sbf, 16)) << 16);
      dat32[ni][0] = p;
      dat32[ni][1] = __shfl_down(p, 32);
      if (t == T_ - 1) {
        const size_t idx = (size_t)brow * 1024 + hL[ni];
        outH[idx] = hv; outC[idx] = cn;
      }
    }
    if (l4 == 0) {   // lanes 0..15: one 16B store covers h hbase0..hbase0+7
      uint4v dat;
      dat.x = dat32[0][0]; dat.y = dat32[0][1];
      dat.z = dat32[1][0]; dat.w = dat32[1][1];
      const unsigned long long addr =
          (unsigned long long)(Hout + (size_t)brow * 1024 + hbase0);
      asm volatile("global_store_dwordx4 %0, %1, off sc0 sc1"
                   :: "v"(addr), "v"(dat) : "memory");
    }

    if (t < T_ - 1) {
      // ---- arrive (per wave): own H stores drained -> slot = t+1 ----
      asm volatile("s_waitcnt vmcnt(0)" ::: "memory");
      if (lane == 0) sc_store_u32(myslot, (unsigned int)(t + 1));

      // prefetch next-step x-gather (issued AFTER the arrival so it never
      // delays it; drained by the NEXT step's poll vmcnt(0) — overlapped)
#pragma unroll
      for (int ni = 0; ni < 2; ++ni)
#pragma unroll
        for (int r = 0; r < 4; ++r)
          xgn[ni][r] = xw_of(r)[(size_t)tok2 * 1024 + hL[ni]];
    }
  }
}

// ---------------------------------------------------------------------------
// Y = Hseq(16384x1024 bf16) @ ywT^T + bias -> fp32. m97-style 128x128, BK=32.
// 4096 WGs, XCD-swizzled bid (4096%8==0 -> bijective), waves 2x2, tile 64x64.
// ---------------------------------------------------------------------------
__launch_bounds__(256, 1)
__global__ void out_gemm_kernel(const unsigned short* __restrict__ A,   // [16384][1024] bf16
                                const unsigned short* __restrict__ Bw,  // ywT [4096][1024] bf16
                                const float* __restrict__ bias,         // [4096]
                                float* __restrict__ Yout) {             // [16384][4096] f32
  __shared__ unsigned char Ash[2][8192];   // 128 rows x 64B, XOR-swizzled
  __shared__ unsigned char Bsh[2][8192];
  const int tid = threadIdx.x;
  const int wave = tid >> 6, lane = tid & 63;
  const int wm = wave >> 1, wn = wave & 1;
  const int bid = (blockIdx.x & 7) * 512 + (blockIdx.x >> 3);   // XCD swizzle
  const int tn = bid & 31, tm = bid >> 5;

  const char* Agb = (const char*)(A + (size_t)tm * 128 * 1024);
  const char* Bgb = (const char*)(Bw + (size_t)tn * 128 * 1024);

  f32x4 acc[4][4];
  const f32x4 zz = {0.f, 0.f, 0.f, 0.f};
#pragma unroll
  for (int mi = 0; mi < 4; ++mi)
#pragma unroll
    for (int ni = 0; ni < 4; ++ni) acc[mi][ni] = zz;

  auto stage = [&](int buf, int kc) {
#pragma unroll
    for (int j = 0; j < 2; ++j) {
      const int wbase = wave * 2048 + j * 1024;
      const int D = wbase + lane * 16;
      const int row = D >> 6, off = D & 63;
      const int so = off ^ ((row & 3) << 4);
      gload_lds16(Agb + (size_t)row * 2048 + kc * 64 + so, &Ash[buf][wbase]);
      gload_lds16(Bgb + (size_t)row * 2048 + kc * 64 + so, &Bsh[buf][wbase]);
    }
  };

  stage(0, 0);
  __syncthreads();

#pragma unroll 1
  for (int kc = 0; kc < 32; ++kc) {
    const int cur = kc & 1;
    if (kc < 31) stage(cur ^ 1, kc + 1);
    short8 a[4], b[4];
#pragma unroll
    for (int mi = 0; mi < 4; ++mi) {
      const int row = wm * 64 + mi * 16 + (lane & 15);
      const int off = ((lane >> 4) * 16) ^ ((row & 3) << 4);
      a[mi] = *(const short8*)&Ash[cur][row * 64 + off];
    }
#pragma unroll
    for (int ni = 0; ni < 4; ++ni) {
      const int row = wn * 64 + ni * 16 + (lane & 15);
      const int off = ((lane >> 4) * 16) ^ ((row & 3) << 4);
      b[ni] = *(const short8*)&Bsh[cur][row * 64 + off];
    }
#pragma unroll
    for (int mi = 0; mi < 4; ++mi)
#pragma unroll
      for (int ni = 0; ni < 4; ++ni)
        acc[mi][ni] = __builtin_amdgcn_mfma_f32_16x16x32_bf16(a[mi], b[ni], acc[mi][ni], 0, 0, 0);
    __syncthreads();
  }

  const int l15 = lane & 15, l4 = lane >> 4;
#pragma unroll
  for (int ni = 0; ni < 4; ++ni) {
    const int n = tn * 128 + wn * 64 + ni * 16 + l15;
    const float bv = bias[n];
#pragma unroll
    for (int mi = 0; mi < 4; ++mi) {
#pragma unroll
      for (int r = 0; r < 4; ++r) {
        const int m = tm * 128 + wm * 64 + mi * 16 + l4 * 4 + r;
        Yout[(size_t)m * 4096 + n] = acc[mi][ni][r] + bv;
      }
    }
  }
}

// ---------------------------------------------------------------------------
extern "C" void kernel_launch(void* const* d_in, const int* in_sizes, int n_in,
                              void* d_out, int out_size, void* d_ws, size_t ws_size,
                              hipStream_t stream) {
  const int* tokens   = (const int*)d_in[0];
  const float* H0     = (const float*)d_in[1];
  const float* C0     = (const float*)d_in[2];
  const float* f_w_xh = (const float*)d_in[3];
  const float* f_w_hh = (const float*)d_in[4];
  const float* f_b    = (const float*)d_in[5];
  const float* i_w_xh = (const float*)d_in[6];
  const float* i_w_hh = (const float*)d_in[7];
  const float* i_b    = (const float*)d_in[8];
  const float* c_w_xh = (const float*)d_in[9];
  const float* c_w_hh = (const float*)d_in[10];
  const float* c_b    = (const float*)d_in[11];
  const float* o_w_xh = (const float*)d_in[12];
  const float* o_w_hh = (const float*)d_in[13];
  const float* o_b    = (const float*)d_in[14];
  const float* y_w_ho = (const float*)d_in[15];
  const float* y_b_o  = (const float*)d_in[16];

  char* ws = (char*)d_ws;
  unsigned short* Wcat = (unsigned short*)ws;                         // 8 MB
  unsigned short* ywT  = (unsigned short*)(ws + (size_t)(8u << 20));  // 8 MB
  unsigned short* Hbuf = (unsigned short*)(ws + (size_t)(16u << 20)); // 257*65536*2 B
  unsigned int* arr = (unsigned int*)(ws + (size_t)(16u << 20) + (size_t)257 * 65536 * 2);
  const size_t needed = (size_t)(16u << 20) + (size_t)257 * 65536 * 2 + 2048;
  if (ws_size < needed) return;  // workspace too small: fail visibly

  const dim3 thr(256);
  hipLaunchKernelGGL(prep_kernel, dim3(16, 64, 6), thr, 0, stream,
                     f_w_hh, i_w_hh, c_w_hh, o_w_hh, y_w_ho,
                     Wcat, ywT, H0, Hbuf, arr);

  float* outH = (float*)d_out + (size_t)T_ * B_ * V_;
  hipLaunchKernelGGL(lstm_persistent_kernel, dim3(NWG), thr, 0, stream,
                     Wcat, Hbuf, arr, C0,
                     f_w_xh, i_w_xh, c_w_xh, o_w_xh,
                     f_b, i_b, c_b, o_b,
                     tokens, outH, outH + 65536);

  hipLaunchKernelGGL(out_gemm_kernel, dim3(4096), thr, 0, stream,
                     Hbuf + 65536, ywT, y_b_o, (float*)d_out);
}